// Round 3
// baseline (196.623 us; speedup 1.0000x reference)
//
#include <hip/hip_runtime.h>
#include <hip/hip_bf16.h>

// Conv2d 3x3 pad=1 stride=1, B=32, 256->256, 56x56, fp32 in/out.
// Implicit GEMM, 256x128 tile, BK=32, 4 waves, 32x32x16 MFMA, k-sliced
// phases (no frag re-reads), 3-buffer distance-2 pipeline, 1 barrier/K-tile,
// counted vmcnt(6), XOR swizzle for 64B rows, 2 blocks/CU.

#define BB    32
#define CINC  256
#define COUTC 256
#define HH    56
#define WW    56
#define HP    58
#define WP    58
#define PIX_PER_IMG 3136
#define NPIX  100352
#define KTOT  2304
#define NKT   72                     // K-tiles of 32

#define XT_BYTES ((size_t)BB*HP*WP*CINC*2)
#define WR_ELEMS ((size_t)COUTC*KTOT)
#define WR_BYTES (WR_ELEMS*2)

#define BUF_SZ 24576                 // A 16KB + B 8KB
#define B_OFF  16384

using frag_t = __attribute__((ext_vector_type(8))) short;   // 8 bf16
using f32x16 = __attribute__((ext_vector_type(16))) float;

__device__ __forceinline__ void gload_lds16(const void* gsrc, void* ldst) {
  __builtin_amdgcn_global_load_lds(
      (const __attribute__((address_space(1))) unsigned*)gsrc,
      (__attribute__((address_space(3))) unsigned*)ldst, 16, 0, 0);
}

// ---------- pre-pass 1: NCHW fp32 -> padded channels-last bf16 Xt[b][58][58][256]
__global__ void xpose_kernel(const float* __restrict__ inp,
                             __hip_bfloat16* __restrict__ xt) {
  int bid = blockIdx.x;
  int hp = bid % HP;
  int t  = bid / HP;
  int cb = t % 4;
  int b  = t / 4;
  __shared__ __hip_bfloat16 tile[64 * 60];
  int tid = threadIdx.x;
  for (int i = tid; i < 64 * 60; i += 256) tile[i] = __float2bfloat16(0.f);
  __syncthreads();
  int h = hp - 1;
  if (h >= 0 && h < HH) {
    const float* src = inp + ((size_t)(b * CINC + cb * 64) * HH + h) * WW;
    for (int i = tid; i < 64 * WW; i += 256) {
      int ci = i / WW, w = i - ci * WW;
      tile[ci * 60 + (w + 1)] = __float2bfloat16(src[(size_t)ci * HH * WW + w]);
    }
  }
  __syncthreads();
  __hip_bfloat16* dst = xt + ((size_t)(b * HP + hp) * WP) * CINC + cb * 64;
  for (int i = tid; i < WP * 64; i += 256) {
    int wp = i >> 6, ci = i & 63;
    dst[(size_t)wp * CINC + ci] = tile[ci * 60 + wp];
  }
}

// ---------- pre-pass 2: OIHW fp32 -> Wr[co][k] bf16, k = tap*256 + ci
__global__ void wprep_kernel(const float* __restrict__ k4,
                             __hip_bfloat16* __restrict__ wr) {
  int i = blockIdx.x * 256 + threadIdx.x;
  if (i >= (int)WR_ELEMS) return;
  int co = i / KTOT;
  int k  = i - co * KTOT;
  int tap = k >> 8;
  int ci  = k & 255;
  wr[i] = __float2bfloat16(k4[(co * CINC + ci) * 9 + tap]);
}

// ---------- main kernel
__global__ __launch_bounds__(256, 2) void conv_mfma32(
    const __hip_bfloat16* __restrict__ xt,
    const __hip_bfloat16* __restrict__ wr,
    const float* __restrict__ bias,
    float* __restrict__ out) {
  __shared__ alignas(16) char lds[3 * BUF_SZ];   // 72 KiB -> 2 blocks/CU

  const int tid  = threadIdx.x;
  const int lane = tid & 63;
  const int wid  = tid >> 6;          // 0..3
  const int wm   = wid >> 1;          // co half (rows wm*128..+127)
  const int wn   = wid & 1;           // px half (cols wn*64..+63)
  const int l31  = lane & 31;
  const int lhi  = lane >> 5;

  const int bid   = blockIdx.x;
  const int ntile = (bid & 7) * 98 + (bid >> 3);   // 784 = 8*98, bijective

  const char* wr_b = (const char*)wr;
  const char* xt_b = (const char*)xt;

  // staging: inst = 1KB = 16 rows x 64B. lane l -> row l>>2, phys chunk l&3.
  // phys = logical ^ (row&3)  => source logical chunk = (l&3) ^ ((l>>2)&3).
  const int lr = lane >> 2;
  const int sc = (((lane & 3) ^ (lr & 3)) << 4);

  const char* pA0 = wr_b + (size_t)(wid * 64 +  0 + lr) * (KTOT * 2) + sc;
  const char* pA1 = wr_b + (size_t)(wid * 64 + 16 + lr) * (KTOT * 2) + sc;
  const char* pA2 = wr_b + (size_t)(wid * 64 + 32 + lr) * (KTOT * 2) + sc;
  const char* pA3 = wr_b + (size_t)(wid * 64 + 48 + lr) * (KTOT * 2) + sc;

  auto mkB = [&](int jb) -> const char* {
    int px = ntile * 128 + (wid * 2 + jb) * 16 + lr;
    int b  = px / PIX_PER_IMG;
    int hw = px - b * PIX_PER_IMG;
    int h = hw / WW, w = hw - h * WW;
    return xt_b + (size_t)((b * HP + h) * WP + w) * (CINC * 2) + sc;
  };
  const char* pB0 = mkB(0);
  const char* pB1 = mkB(1);

#define STG_A(WB, T2) {                                                    \
    size_t _ao = (size_t)(T2) * 64;                                        \
    gload_lds16(pA0 + _ao, lds + (WB)*BUF_SZ + (wid * 4 + 0) * 1024);      \
    gload_lds16(pA1 + _ao, lds + (WB)*BUF_SZ + (wid * 4 + 1) * 1024);      \
    gload_lds16(pA2 + _ao, lds + (WB)*BUF_SZ + (wid * 4 + 2) * 1024); }

#define STG_B(WB, T2) {                                                    \
    int _tap = (T2) >> 3; int _rr = _tap / 3, _ss = _tap - _rr * 3;        \
    size_t _ao = (size_t)(T2) * 64;                                        \
    size_t _bo = (size_t)(_rr * WP + _ss) * (CINC * 2)                     \
               + (size_t)((T2) & 7) * 64;                                  \
    gload_lds16(pA3 + _ao, lds + (WB)*BUF_SZ + (wid * 4 + 3) * 1024);      \
    gload_lds16(pB0 + _bo, lds + (WB)*BUF_SZ + B_OFF + (wid*2+0) * 1024);  \
    gload_lds16(pB1 + _bo, lds + (WB)*BUF_SZ + B_OFF + (wid*2+1) * 1024); }

  // frag reads: row = base + l31; logical chunk = ks*2 + lhi; phys = ^(row&3)
  const int aoff  = (wm * 128 + l31) * 64;
  const int boffr = (wn * 64 + l31) * 64;
  const int ck0   = ((lhi ^ (l31 & 3)) << 4);
  const int ck1   = (((2 + lhi) ^ (l31 & 3)) << 4);

  frag_t fa0[4], fb0[2], fa1[4], fb1[2];
  f32x16 acc[4][2] = {};

#define RSL(RB, CK, FA, FB) {                                              \
    const char* _b = lds + (RB)*BUF_SZ;                                    \
    _Pragma("unroll") for (int m = 0; m < 4; ++m)                          \
      FA[m] = *(const frag_t*)(_b + aoff + m * 2048 + (CK));               \
    _Pragma("unroll") for (int n = 0; n < 2; ++n)                          \
      FB[n] = *(const frag_t*)(_b + B_OFF + boffr + n * 2048 + (CK)); }

#define MF(FA, FB) {                                                       \
    _Pragma("unroll") for (int m = 0; m < 4; ++m)                          \
    _Pragma("unroll") for (int n = 0; n < 2; ++n)                          \
      acc[m][n] = __builtin_amdgcn_mfma_f32_32x32x16_bf16(                 \
          FA[m], FB[n], acc[m][n], 0, 0, 0); }

#define BODY(T, RB, WB, NB) {                                              \
    RSL(RB, ck1, fa1, fb1);                                                \
    STG_A(WB, (T) + 2);                                                    \
    MF(fa0, fb0);                                                          \
    STG_B(WB, (T) + 2);                                                    \
    asm volatile("s_waitcnt lgkmcnt(0)" ::: "memory");                     \
    asm volatile("s_waitcnt vmcnt(6)" ::: "memory");                       \
    __builtin_amdgcn_s_barrier();                                          \
    __builtin_amdgcn_sched_barrier(0);                                     \
    RSL(NB, ck0, fa0, fb0);                                                \
    MF(fa1, fb1); }

  // ---- prologue: stage tiles 0 and 1
  STG_A(0, 0); STG_B(0, 0);
  STG_A(1, 1); STG_B(1, 1);
  asm volatile("s_waitcnt vmcnt(6)" ::: "memory");
  __builtin_amdgcn_s_barrier();
  __builtin_amdgcn_sched_barrier(0);
  RSL(0, ck0, fa0, fb0);

  for (int base = 0; base < 69; base += 3) {
    BODY(base + 0, 0, 2, 1);
    BODY(base + 1, 1, 0, 2);
    BODY(base + 2, 2, 1, 0);
  }
  BODY(69, 0, 2, 1);

  // ---- t = 70: no staging, full drain for the last buffer
  {
    RSL(1, ck1, fa1, fb1);
    MF(fa0, fb0);
    asm volatile("s_waitcnt lgkmcnt(0)" ::: "memory");
    asm volatile("s_waitcnt vmcnt(0)" ::: "memory");
    __builtin_amdgcn_s_barrier();
    __builtin_amdgcn_sched_barrier(0);
    RSL(2, ck0, fa0, fb0);
    MF(fa1, fb1);
  }
  // ---- t = 71: tail
  {
    RSL(2, ck1, fa1, fb1);
    MF(fa0, fb0);
    MF(fa1, fb1);
  }

  // ---- epilogue: D 32x32 layout col=l31 (px), row=(r&3)+8*(r>>2)+4*lhi (co)
  int pb[2], phw[2];
#pragma unroll
  for (int n = 0; n < 2; ++n) {
    int pxg = ntile * 128 + wn * 64 + n * 32 + l31;
    pb[n]  = pxg / PIX_PER_IMG;
    phw[n] = pxg - pb[n] * PIX_PER_IMG;
  }
#pragma unroll
  for (int m = 0; m < 4; ++m) {
#pragma unroll
    for (int r = 0; r < 16; ++r) {
      int co = wm * 128 + m * 32 + (r & 3) + 8 * (r >> 2) + 4 * lhi;
      float bv = bias[co];
#pragma unroll
      for (int n = 0; n < 2; ++n)
        out[((size_t)pb[n] * COUTC + co) * PIX_PER_IMG + phw[n]] =
            acc[m][n][r] + bv;
    }
  }
}

// ---------- correctness fallback if workspace is too small
__global__ void conv_direct(const float* __restrict__ inp,
                            const float* __restrict__ kern,
                            const float* __restrict__ bias,
                            float* __restrict__ out) {
  int idx = blockIdx.x * 256 + threadIdx.x;
  if (idx >= BB * COUTC * PIX_PER_IMG) return;
  int w = idx % WW;
  int t = idx / WW;
  int h = t % HH; t /= HH;
  int co = t % COUTC;
  int b  = t / COUTC;
  float acc = bias[co];
  for (int ci = 0; ci < CINC; ++ci)
    for (int r = 0; r < 3; ++r) {
      int hh = h + r - 1;
      if (hh < 0 || hh >= HH) continue;
      for (int s = 0; s < 3; ++s) {
        int ww2 = w + s - 1;
        if (ww2 < 0 || ww2 >= WW) continue;
        acc += inp[((size_t)(b * CINC + ci) * HH + hh) * WW + ww2] *
               kern[(co * CINC + ci) * 9 + r * 3 + s];
      }
    }
  out[idx] = acc;
}

extern "C" void kernel_launch(void* const* d_in, const int* in_sizes, int n_in,
                              void* d_out, int out_size, void* d_ws, size_t ws_size,
                              hipStream_t stream) {
  const float* inp  = (const float*)d_in[0];
  const float* kern = (const float*)d_in[1];
  const float* bias = (const float*)d_in[2];
  float* out = (float*)d_out;

  size_t need = XT_BYTES + WR_BYTES;
  if (ws_size < need) {
    int tot = BB * COUTC * PIX_PER_IMG;
    conv_direct<<<(tot + 255) / 256, 256, 0, stream>>>(inp, kern, bias, out);
    return;
  }

  __hip_bfloat16* xt  = (__hip_bfloat16*)d_ws;
  __hip_bfloat16* wrp = (__hip_bfloat16*)((char*)d_ws + XT_BYTES);

  xpose_kernel<<<BB * 4 * HP, 256, 0, stream>>>(inp, xt);
  wprep_kernel<<<(int)((WR_ELEMS + 255) / 256), 256, 0, stream>>>(kern, wrp);
  conv_mfma32<<<NPIX / 128, 256, 0, stream>>>(xt, wrp, bias, out);
}

// Round 4
// 185.978 us; speedup vs baseline: 1.0572x; 1.0572x over previous
//
#include <hip/hip_runtime.h>
#include <hip/hip_bf16.h>

// Conv2d 3x3 pad=1 stride=1, B=32, 256->256, 56x56, fp32 in/out.
// Implicit GEMM. Block 256co x 128px, 4 waves (wave tile 128x64), BK=32,
// 16x16x32 MFMA, 3-buffer distance-2 pipeline, 1 barrier + 1 vmcnt(6) per
// K-tile, 64B-row swizzle phys_chunk=(g+(row>>1))&3 (conflict-free for the
// 16-row x 4-chunk b128 read pattern), 2 blocks/CU, XCD-aware block swizzle.

#define BB    32
#define CINC  256
#define COUTC 256
#define HH    56
#define WW    56
#define HP    58
#define WP    58
#define PIX_PER_IMG 3136
#define NPIX  100352
#define KTOT  2304
#define NKT   72                     // K-tiles of 32

#define XT_BYTES ((size_t)BB*HP*WP*CINC*2)
#define WR_ELEMS ((size_t)COUTC*KTOT)
#define WR_BYTES (WR_ELEMS*2)

#define BUF_SZ 24576                 // A 16KB + B 8KB
#define B_OFF  16384

using frag_t = __attribute__((ext_vector_type(8))) short;   // 8 bf16
using f32x4  = __attribute__((ext_vector_type(4))) float;

__device__ __forceinline__ void gload_lds16(const void* gsrc, void* ldst) {
  __builtin_amdgcn_global_load_lds(
      (const __attribute__((address_space(1))) unsigned*)gsrc,
      (__attribute__((address_space(3))) unsigned*)ldst, 16, 0, 0);
}

// ---------- pre-pass 1: NCHW fp32 -> padded channels-last bf16 Xt[b][58][58][256]
__global__ void xpose_kernel(const float* __restrict__ inp,
                             __hip_bfloat16* __restrict__ xt) {
  int bid = blockIdx.x;
  int hp = bid % HP;
  int t  = bid / HP;
  int cb = t % 4;
  int b  = t / 4;
  __shared__ __hip_bfloat16 tile[64 * 60];
  int tid = threadIdx.x;
  for (int i = tid; i < 64 * 60; i += 256) tile[i] = __float2bfloat16(0.f);
  __syncthreads();
  int h = hp - 1;
  if (h >= 0 && h < HH) {
    const float* src = inp + ((size_t)(b * CINC + cb * 64) * HH + h) * WW;
    for (int i = tid; i < 64 * WW; i += 256) {
      int ci = i / WW, w = i - ci * WW;
      tile[ci * 60 + (w + 1)] = __float2bfloat16(src[(size_t)ci * HH * WW + w]);
    }
  }
  __syncthreads();
  __hip_bfloat16* dst = xt + ((size_t)(b * HP + hp) * WP) * CINC + cb * 64;
  for (int i = tid; i < WP * 64; i += 256) {
    int wp = i >> 6, ci = i & 63;
    dst[(size_t)wp * CINC + ci] = tile[ci * 60 + wp];
  }
}

// ---------- pre-pass 2: OIHW fp32 -> Wr[co][k] bf16, k = tap*256 + ci
__global__ void wprep_kernel(const float* __restrict__ k4,
                             __hip_bfloat16* __restrict__ wr) {
  int i = blockIdx.x * 256 + threadIdx.x;
  if (i >= (int)WR_ELEMS) return;
  int co = i / KTOT;
  int k  = i - co * KTOT;
  int tap = k >> 8;
  int ci  = k & 255;
  wr[i] = __float2bfloat16(k4[(co * CINC + ci) * 9 + tap]);
}

// ---------- main kernel
__global__ __launch_bounds__(256, 2) void conv_p16(
    const __hip_bfloat16* __restrict__ xt,
    const __hip_bfloat16* __restrict__ wr,
    const float* __restrict__ bias,
    float* __restrict__ out) {
  __shared__ alignas(16) char lds[3 * BUF_SZ];   // 72 KiB -> 2 blocks/CU

  const int tid  = threadIdx.x;
  const int lane = tid & 63;
  const int wid  = tid >> 6;          // 0..3
  const int wm   = wid >> 1;          // co half (rows wm*128..+127)
  const int wn   = wid & 1;           // px half (cols wn*64..+63)
  const int fr   = lane & 15;
  const int g    = lane >> 4;         // 0..3 k-chunk

  const int bid   = blockIdx.x;
  const int ntile = (bid & 7) * 98 + (bid >> 3);   // 784 = 8*98, bijective

  const char* wr_b = (const char*)wr;
  const char* xt_b = (const char*)xt;

  // staging: 1KB gload = 16 rows x 64B. lane l -> row r=l>>2, phys chunk l&3.
  // swizzle: LDS[row][phys] holds logical chunk (phys - ((row>>1)&3)) & 3.
  const int lr  = lane >> 2;                              // row-in-block 0..15
  const int sc  = ((((lane & 3) - ((lane >> 3) & 3)) & 3) << 4);  // src byte off

  // A: wave w stages rows [w*64, w*64+64), 4 gloads
  const char* pA0 = wr_b + (size_t)(wid * 64 +  0 + lr) * (KTOT * 2) + sc;
  const char* pA1 = wr_b + (size_t)(wid * 64 + 16 + lr) * (KTOT * 2) + sc;
  const char* pA2 = wr_b + (size_t)(wid * 64 + 32 + lr) * (KTOT * 2) + sc;
  const char* pA3 = wr_b + (size_t)(wid * 64 + 48 + lr) * (KTOT * 2) + sc;

  // B: wave w stages rows [w*32, w*32+32), 2 gloads
  auto mkB = [&](int jb) -> const char* {
    int px = ntile * 128 + wid * 32 + jb * 16 + lr;
    int b  = px / PIX_PER_IMG;
    int hw = px - b * PIX_PER_IMG;
    int h = hw / WW, w = hw - h * WW;
    return xt_b + (size_t)((b * HP + h) * WP + w) * (CINC * 2) + sc;
  };
  const char* pB0 = mkB(0);
  const char* pB1 = mkB(1);

#define STG(T2, WB) {                                                      \
    size_t _ao = (size_t)(T2) * 64;                                        \
    int _tap = (T2) >> 3; int _rr = _tap / 3, _ss = _tap - _rr * 3;        \
    size_t _bo = (size_t)(_rr * WP + _ss) * (CINC * 2)                     \
               + (size_t)((T2) & 7) * 64;                                  \
    char* _d = lds + (WB) * BUF_SZ;                                        \
    gload_lds16(pA0 + _ao, _d + wid * 4096 + 0);                           \
    gload_lds16(pA1 + _ao, _d + wid * 4096 + 1024);                        \
    gload_lds16(pA2 + _ao, _d + wid * 4096 + 2048);                        \
    gload_lds16(pA3 + _ao, _d + wid * 4096 + 3072);                        \
    gload_lds16(pB0 + _bo, _d + B_OFF + wid * 2048 + 0);                   \
    gload_lds16(pB1 + _bo, _d + B_OFF + wid * 2048 + 1024); }

  // frag reads: row = base + fr (base mult of 16) -> chunk = (g + (fr>>1)) & 3
  const int ckr   = (((g + (fr >> 1)) & 3) << 4);
  const int aroff = (wm * 128 + fr) * 64 + ckr;
  const int broff = B_OFF + (wn * 64 + fr) * 64 + ckr;

  frag_t fa[8], fb[4];
  f32x4 acc[8][4] = {};

#define RSL(RB) {                                                          \
    const char* _b = lds + (RB) * BUF_SZ;                                  \
    _Pragma("unroll") for (int m = 0; m < 8; ++m)                          \
      fa[m] = *(const frag_t*)(_b + aroff + m * 1024);                     \
    _Pragma("unroll") for (int n = 0; n < 4; ++n)                          \
      fb[n] = *(const frag_t*)(_b + broff + n * 1024); }

#define MF() {                                                             \
    __builtin_amdgcn_s_setprio(1);                                         \
    _Pragma("unroll") for (int m = 0; m < 8; ++m)                          \
    _Pragma("unroll") for (int n = 0; n < 4; ++n)                          \
      acc[m][n] = __builtin_amdgcn_mfma_f32_16x16x32_bf16(                 \
          fa[m], fb[n], acc[m][n], 0, 0, 0);                               \
    __builtin_amdgcn_s_setprio(0); }

#define BODY(T, RB, WB) {                                                  \
    STG((T) + 2, WB);                                                      \
    RSL(RB);                                                               \
    MF();                                                                  \
    asm volatile("s_waitcnt vmcnt(6)" ::: "memory");                       \
    __builtin_amdgcn_s_barrier();                                          \
    __builtin_amdgcn_sched_barrier(0); }

  // ---- prologue: stage tiles 0 (buf0) and 1 (buf1)
  STG(0, 0);
  STG(1, 1);
  asm volatile("s_waitcnt vmcnt(6)" ::: "memory");   // tile 0 landed
  __builtin_amdgcn_s_barrier();
  __builtin_amdgcn_sched_barrier(0);

  // bodies t = 0..68 (23 x 3), ring: read t%3, write (t+2)%3
  for (int base = 0; base < 69; base += 3) {
    BODY(base + 0, 0, 2);
    BODY(base + 1, 1, 0);
    BODY(base + 2, 2, 1);
  }
  // t = 69: stage 71 -> buf2, read buf0
  BODY(69, 0, 2);
  // t = 70: read buf1, no staging, full drain for last buffer
  {
    RSL(1);
    MF();
    asm volatile("s_waitcnt vmcnt(0)" ::: "memory");
    __builtin_amdgcn_s_barrier();
    __builtin_amdgcn_sched_barrier(0);
  }
  // t = 71: read buf2
  {
    RSL(2);
    MF();
  }

  // ---- epilogue: D layout col=lane&15 (px), row=(lane>>4)*4+reg (co)
  int pb[4], phw[4];
#pragma unroll
  for (int n = 0; n < 4; ++n) {
    int pxg = ntile * 128 + wn * 64 + n * 16 + fr;
    pb[n]  = pxg / PIX_PER_IMG;
    phw[n] = pxg - pb[n] * PIX_PER_IMG;
  }
#pragma unroll
  for (int m = 0; m < 8; ++m) {
#pragma unroll
    for (int rg = 0; rg < 4; ++rg) {
      int co = wm * 128 + m * 16 + g * 4 + rg;
      float bv = bias[co];
#pragma unroll
      for (int n = 0; n < 4; ++n)
        out[((size_t)pb[n] * COUTC + co) * PIX_PER_IMG + phw[n]] =
            acc[m][n][rg] + bv;
    }
  }
}

// ---------- correctness fallback if workspace is too small
__global__ void conv_direct(const float* __restrict__ inp,
                            const float* __restrict__ kern,
                            const float* __restrict__ bias,
                            float* __restrict__ out) {
  int idx = blockIdx.x * 256 + threadIdx.x;
  if (idx >= BB * COUTC * PIX_PER_IMG) return;
  int w = idx % WW;
  int t = idx / WW;
  int h = t % HH; t /= HH;
  int co = t % COUTC;
  int b  = t / COUTC;
  float acc = bias[co];
  for (int ci = 0; ci < CINC; ++ci)
    for (int r = 0; r < 3; ++r) {
      int hh = h + r - 1;
      if (hh < 0 || hh >= HH) continue;
      for (int s = 0; s < 3; ++s) {
        int ww2 = w + s - 1;
        if (ww2 < 0 || ww2 >= WW) continue;
        acc += inp[((size_t)(b * CINC + ci) * HH + hh) * WW + ww2] *
               kern[(co * CINC + ci) * 9 + r * 3 + s];
      }
    }
  out[idx] = acc;
}

extern "C" void kernel_launch(void* const* d_in, const int* in_sizes, int n_in,
                              void* d_out, int out_size, void* d_ws, size_t ws_size,
                              hipStream_t stream) {
  const float* inp  = (const float*)d_in[0];
  const float* kern = (const float*)d_in[1];
  const float* bias = (const float*)d_in[2];
  float* out = (float*)d_out;

  size_t need = XT_BYTES + WR_BYTES;
  if (ws_size < need) {
    int tot = BB * COUTC * PIX_PER_IMG;
    conv_direct<<<(tot + 255) / 256, 256, 0, stream>>>(inp, kern, bias, out);
    return;
  }

  __hip_bfloat16* xt  = (__hip_bfloat16*)d_ws;
  __hip_bfloat16* wrp = (__hip_bfloat16*)((char*)d_ws + XT_BYTES);

  xpose_kernel<<<BB * 4 * HP, 256, 0, stream>>>(inp, xt);
  wprep_kernel<<<(int)((WR_ELEMS + 255) / 256), 256, 0, stream>>>(kern, wrp);
  conv_p16<<<NPIX / 128, 256, 0, stream>>>(xt, wrp, bias, out);
}

// Round 5
// 185.545 us; speedup vs baseline: 1.0597x; 1.0023x over previous
//
#include <hip/hip_runtime.h>
#include <hip/hip_bf16.h>

// Conv2d 3x3 pad=1 stride=1, B=32, 256->256, 56x56, fp32 in/out.
// Implicit GEMM. Block 256co x 128px, 4 waves (wave tile 128x64), BK=32,
// 16x16x32 MFMA. A (weights) pre-packed in fragment order and loaded
// DIRECTLY global->VGPR (L1/L2-resident, reg double-buffer); B staged in a
// 3-buffer LDS ring (conflict-free 64B-row swizzle), 1 barrier + counted
// vmcnt(10) per K-tile. LDS 24KB/block -> multiple blocks/CU.

#define BB    32
#define CINC  256
#define COUTC 256
#define HH    56
#define WW    56
#define HP    58
#define WP    58
#define PIX_PER_IMG 3136
#define NPIX  100352
#define KTOT  2304
#define NKT   72                     // K-tiles of 32

#define XT_BYTES ((size_t)BB*HP*WP*CINC*2)
#define AWR_FRAGS (72*16*64)         // (t, mb, lane) 16B frags
#define AWR_BYTES ((size_t)AWR_FRAGS*16)

#define BUF_SZ 8192                  // B only: 128 rows x 64B

using frag_t = __attribute__((ext_vector_type(8))) short;   // 8 bf16
using f32x4  = __attribute__((ext_vector_type(4))) float;

__device__ __forceinline__ void gload_lds16(const void* gsrc, void* ldst) {
  __builtin_amdgcn_global_load_lds(
      (const __attribute__((address_space(1))) unsigned*)gsrc,
      (__attribute__((address_space(3))) unsigned*)ldst, 16, 0, 0);
}

// ---------- pre-pass 1: NCHW fp32 -> padded channels-last bf16 Xt[b][58][58][256]
__global__ void xpose_kernel(const float* __restrict__ inp,
                             __hip_bfloat16* __restrict__ xt) {
  int bid = blockIdx.x;
  int hp = bid % HP;
  int t  = bid / HP;
  int cb = t % 4;
  int b  = t / 4;
  __shared__ __hip_bfloat16 tile[64 * 60];
  int tid = threadIdx.x;
  for (int i = tid; i < 64 * 60; i += 256) tile[i] = __float2bfloat16(0.f);
  __syncthreads();
  int h = hp - 1;
  if (h >= 0 && h < HH) {
    const float* src = inp + ((size_t)(b * CINC + cb * 64) * HH + h) * WW;
    for (int i = tid; i < 64 * WW; i += 256) {
      int ci = i / WW, w = i - ci * WW;
      tile[ci * 60 + (w + 1)] = __float2bfloat16(src[(size_t)ci * HH * WW + w]);
    }
  }
  __syncthreads();
  __hip_bfloat16* dst = xt + ((size_t)(b * HP + hp) * WP) * CINC + cb * 64;
  for (int i = tid; i < WP * 64; i += 256) {
    int wp = i >> 6, ci = i & 63;
    dst[(size_t)wp * CINC + ci] = tile[ci * 60 + wp];
  }
}

// ---------- pre-pass 2: OIHW fp32 -> fragment-ordered Awr[t][mb][lane] (16B)
// lane l of frag (t, mb) holds A[co = mb*16 + (l&15)][k = t*32 + (l>>4)*8 + j],
// j = 0..7, with k = tap*256 + ci (tap = k>>8, ci = k&255).
__global__ void wprep_pack(const float* __restrict__ k4,
                           frag_t* __restrict__ awr) {
  int i = blockIdx.x * 256 + threadIdx.x;   // (t*16 + mb)*64 + lane
  if (i >= AWR_FRAGS) return;
  int lane = i & 63;
  int mb   = (i >> 6) & 15;
  int t    = i >> 10;
  int co   = mb * 16 + (lane & 15);
  int kb   = t * 32 + (lane >> 4) * 8;
  frag_t v;
#pragma unroll
  for (int j = 0; j < 8; ++j) {
    int k = kb + j;
    int tap = k >> 8;
    int ci  = k & 255;
    __hip_bfloat16 h = __float2bfloat16(k4[(co * CINC + ci) * 9 + tap]);
    v[j] = *reinterpret_cast<short*>(&h);
  }
  awr[i] = v;
}

// ---------- main kernel
__global__ __launch_bounds__(256, 2) void conv_areg(
    const __hip_bfloat16* __restrict__ xt,
    const frag_t* __restrict__ awr,
    const float* __restrict__ bias,
    float* __restrict__ out) {
  __shared__ alignas(16) char lds[3 * BUF_SZ];   // 24 KiB

  const int tid  = threadIdx.x;
  const int lane = tid & 63;
  const int wid  = tid >> 6;          // 0..3
  const int wm   = wid >> 1;          // co half (rows wm*128..+127)
  const int wn   = wid & 1;           // px half (cols wn*64..+63)
  const int fr   = lane & 15;
  const int g    = lane >> 4;         // 0..3 k-chunk

  const int bid   = blockIdx.x;
  const int ntile = (bid & 7) * 98 + (bid >> 3);   // 784 = 8*98, bijective

  const char* xt_b = (const char*)xt;

  // B staging: 1KB gload = 16 rows x 64B. lane l -> row l>>2, phys chunk l&3.
  // swizzle: LDS[row][phys] holds logical chunk (phys - ((row>>1)&3)) & 3.
  const int lr  = lane >> 2;                              // row-in-block 0..15
  const int sc  = ((((lane & 3) - ((lane >> 3) & 3)) & 3) << 4);  // src byte off

  auto mkB = [&](int jb) -> const char* {
    int px = ntile * 128 + wid * 32 + jb * 16 + lr;
    int b  = px / PIX_PER_IMG;
    int hw = px - b * PIX_PER_IMG;
    int h = hw / WW, w = hw - h * WW;
    return xt_b + (size_t)((b * HP + h) * WP + w) * (CINC * 2) + sc;
  };
  const char* pB0 = mkB(0);
  const char* pB1 = mkB(1);

#define STG(T2, WB) {                                                      \
    int _tap = (T2) >> 3; int _rr = _tap / 3, _ss = _tap - _rr * 3;        \
    size_t _bo = (size_t)(_rr * WP + _ss) * (CINC * 2)                     \
               + (size_t)((T2) & 7) * 64;                                  \
    char* _d = lds + (WB) * BUF_SZ;                                        \
    gload_lds16(pB0 + _bo, _d + wid * 2048 + 0);                           \
    gload_lds16(pB1 + _bo, _d + wid * 2048 + 1024); }

  // A frag loads: frag index (t*16 + wm*8 + m)*64 + lane  (16B/lane, coalesced)
  const frag_t* abase = awr + (size_t)(wm * 8) * 64 + lane;

#define ALOAD(T1, FA) {                                                    \
    const frag_t* _p = abase + (size_t)(T1) * (16 * 64);                   \
    _Pragma("unroll") for (int m = 0; m < 8; ++m)                          \
      FA[m] = _p[m * 64]; }

  // B frag reads: row = wn*64 + n*16 + fr -> phys chunk (g + (fr>>1)) & 3
  const int ckr   = (((g + (fr >> 1)) & 3) << 4);
  const int broff = (wn * 64 + fr) * 64 + ckr;

  frag_t fa0[8], fa1[8], fb[4];
  f32x4 acc[8][4] = {};

#define RSL(RB) {                                                          \
    const char* _b = lds + (RB) * BUF_SZ;                                  \
    _Pragma("unroll") for (int n = 0; n < 4; ++n)                          \
      fb[n] = *(const frag_t*)(_b + broff + n * 1024); }

#define MF(FA) {                                                           \
    __builtin_amdgcn_s_setprio(1);                                         \
    _Pragma("unroll") for (int m = 0; m < 8; ++m)                          \
    _Pragma("unroll") for (int n = 0; n < 4; ++n)                          \
      acc[m][n] = __builtin_amdgcn_mfma_f32_16x16x32_bf16(                 \
          FA[m], fb[n], acc[m][n], 0, 0, 0);                               \
    __builtin_amdgcn_s_setprio(0); }

  // body t: stage B(t+2), load A(t+1) into FNXT, read B(t), MFMA with FCUR.
  // outstanding VMEM at wait = this body's 2 + 8 -> vmcnt(10) retires the
  // previous body's B-stage (never drains to 0 in the main loop).
#define BODY(T, RB, WB, FCUR, FNXT) {                                      \
    STG((T) + 2, WB);                                                      \
    ALOAD((T) + 1, FNXT);                                                  \
    RSL(RB);                                                               \
    MF(FCUR);                                                              \
    asm volatile("s_waitcnt vmcnt(10)" ::: "memory");                      \
    __builtin_amdgcn_s_barrier();                                          \
    __builtin_amdgcn_sched_barrier(0); }

  // ---- prologue: stage B tiles 0,1; load A tile 0
  STG(0, 0);
  STG(1, 1);
  ALOAD(0, fa0);
  asm volatile("s_waitcnt vmcnt(10)" ::: "memory");   // B(0) landed
  __builtin_amdgcn_s_barrier();
  __builtin_amdgcn_sched_barrier(0);

  // bodies t = 0..65 (11 x 6; ring mod 3, A-parity mod 2)
  for (int base = 0; base < 66; base += 6) {
    BODY(base + 0, 0, 2, fa0, fa1);
    BODY(base + 1, 1, 0, fa1, fa0);
    BODY(base + 2, 2, 1, fa0, fa1);
    BODY(base + 3, 0, 2, fa1, fa0);
    BODY(base + 4, 1, 0, fa0, fa1);
    BODY(base + 5, 2, 1, fa1, fa0);
  }
  BODY(66, 0, 2, fa0, fa1);
  BODY(67, 1, 0, fa1, fa0);
  BODY(68, 2, 1, fa0, fa1);
  BODY(69, 0, 2, fa1, fa0);   // stages B(71), loads A(70)

  // t = 70: load A(71), read buf1, full drain for the last buffer
  {
    ALOAD(71, fa1);
    RSL(1);
    MF(fa0);
    asm volatile("s_waitcnt vmcnt(0)" ::: "memory");
    __builtin_amdgcn_s_barrier();
    __builtin_amdgcn_sched_barrier(0);
  }
  // t = 71
  {
    RSL(2);
    MF(fa1);
  }

  // ---- epilogue: D layout col=lane&15 (px), row=(lane>>4)*4+reg (co)
  int pb[4], phw[4];
#pragma unroll
  for (int n = 0; n < 4; ++n) {
    int pxg = ntile * 128 + wn * 64 + n * 16 + fr;
    pb[n]  = pxg / PIX_PER_IMG;
    phw[n] = pxg - pb[n] * PIX_PER_IMG;
  }
#pragma unroll
  for (int m = 0; m < 8; ++m) {
#pragma unroll
    for (int rg = 0; rg < 4; ++rg) {
      int co = wm * 128 + m * 16 + g * 4 + rg;
      float bv = bias[co];
#pragma unroll
      for (int n = 0; n < 4; ++n)
        out[((size_t)pb[n] * COUTC + co) * PIX_PER_IMG + phw[n]] =
            acc[m][n][rg] + bv;
    }
  }
}

// ---------- correctness fallback if workspace is too small
__global__ void conv_direct(const float* __restrict__ inp,
                            const float* __restrict__ kern,
                            const float* __restrict__ bias,
                            float* __restrict__ out) {
  int idx = blockIdx.x * 256 + threadIdx.x;
  if (idx >= BB * COUTC * PIX_PER_IMG) return;
  int w = idx % WW;
  int t = idx / WW;
  int h = t % HH; t /= HH;
  int co = t % COUTC;
  int b  = t / COUTC;
  float acc = bias[co];
  for (int ci = 0; ci < CINC; ++ci)
    for (int r = 0; r < 3; ++r) {
      int hh = h + r - 1;
      if (hh < 0 || hh >= HH) continue;
      for (int s = 0; s < 3; ++s) {
        int ww2 = w + s - 1;
        if (ww2 < 0 || ww2 >= WW) continue;
        acc += inp[((size_t)(b * CINC + ci) * HH + hh) * WW + ww2] *
               kern[(co * CINC + ci) * 9 + r * 3 + s];
      }
    }
  out[idx] = acc;
}

extern "C" void kernel_launch(void* const* d_in, const int* in_sizes, int n_in,
                              void* d_out, int out_size, void* d_ws, size_t ws_size,
                              hipStream_t stream) {
  const float* inp  = (const float*)d_in[0];
  const float* kern = (const float*)d_in[1];
  const float* bias = (const float*)d_in[2];
  float* out = (float*)d_out;

  size_t need = XT_BYTES + AWR_BYTES;
  if (ws_size < need) {
    int tot = BB * COUTC * PIX_PER_IMG;
    conv_direct<<<(tot + 255) / 256, 256, 0, stream>>>(inp, kern, bias, out);
    return;
  }

  __hip_bfloat16* xt = (__hip_bfloat16*)d_ws;
  frag_t* awr = (frag_t*)((char*)d_ws + XT_BYTES);

  xpose_kernel<<<BB * 4 * HP, 256, 0, stream>>>(inp, xt);
  wprep_pack<<<(AWR_FRAGS + 255) / 256, 256, 0, stream>>>(kern, awr);
  conv_areg<<<NPIX / 128, 256, 0, stream>>>(xt, awr, bias, out);
}

// Round 6
// 184.753 us; speedup vs baseline: 1.0642x; 1.0043x over previous
//
#include <hip/hip_runtime.h>
#include <hip/hip_bf16.h>

// Conv2d 3x3 pad=1 stride=1, B=32, 256->256, 56x56, fp32 in/out.
// Implicit GEMM. Block 128co x 128px, 4 waves (wave tile 64x64), BK=32,
// 16x16x32 MFMA. A (weights) fragment-packed, loaded global->VGPR with
// distance-1 prefetch; B staged via global_load_lds into a 3-buffer ring
// (conflict-free 64B-row swizzle), distance-2, 1 barrier + vmcnt(6)/K-tile.
// 24KB LDS + ~140 VGPR -> 3 blocks/CU = 12 independent waves/CU (m97-style
// implicit overlap). Grid 1568 = 2.04 rounds of 768 resident.

#define BB    32
#define CINC  256
#define COUTC 256
#define HH    56
#define WW    56
#define HP    58
#define WP    58
#define PIX_PER_IMG 3136
#define NPIX  100352
#define KTOT  2304
#define NKT   72                     // K-tiles of 32

#define XT_BYTES ((size_t)BB*HP*WP*CINC*2)
#define AWR_FRAGS (72*16*64)         // (t, mb, lane) 16B frags
#define AWR_BYTES ((size_t)AWR_FRAGS*16)

#define BUF_SZ 8192                  // B only: 128 rows x 64B

using frag_t = __attribute__((ext_vector_type(8))) short;   // 8 bf16
using f32x4  = __attribute__((ext_vector_type(4))) float;

__device__ __forceinline__ void gload_lds16(const void* gsrc, void* ldst) {
  __builtin_amdgcn_global_load_lds(
      (const __attribute__((address_space(1))) unsigned*)gsrc,
      (__attribute__((address_space(3))) unsigned*)ldst, 16, 0, 0);
}

// ---------- pre-pass 1: NCHW fp32 -> padded channels-last bf16 Xt[b][58][58][256]
__global__ void xpose_kernel(const float* __restrict__ inp,
                             __hip_bfloat16* __restrict__ xt) {
  int bid = blockIdx.x;
  int hp = bid % HP;
  int t  = bid / HP;
  int cb = t % 4;
  int b  = t / 4;
  __shared__ __hip_bfloat16 tile[64 * 60];
  int tid = threadIdx.x;
  for (int i = tid; i < 64 * 60; i += 256) tile[i] = __float2bfloat16(0.f);
  __syncthreads();
  int h = hp - 1;
  if (h >= 0 && h < HH) {
    const float* src = inp + ((size_t)(b * CINC + cb * 64) * HH + h) * WW;
    for (int i = tid; i < 64 * WW; i += 256) {
      int ci = i / WW, w = i - ci * WW;
      tile[ci * 60 + (w + 1)] = __float2bfloat16(src[(size_t)ci * HH * WW + w]);
    }
  }
  __syncthreads();
  __hip_bfloat16* dst = xt + ((size_t)(b * HP + hp) * WP) * CINC + cb * 64;
  for (int i = tid; i < WP * 64; i += 256) {
    int wp = i >> 6, ci = i & 63;
    dst[(size_t)wp * CINC + ci] = tile[ci * 60 + wp];
  }
}

// ---------- pre-pass 2: OIHW fp32 -> fragment-ordered Awr[t][mb][lane] (16B)
// lane l of frag (t, mb) holds A[co = mb*16 + (l&15)][k = t*32 + (l>>4)*8 + j]
__global__ void wprep_pack(const float* __restrict__ k4,
                           frag_t* __restrict__ awr) {
  int i = blockIdx.x * 256 + threadIdx.x;   // (t*16 + mb)*64 + lane
  if (i >= AWR_FRAGS) return;
  int lane = i & 63;
  int mb   = (i >> 6) & 15;
  int t    = i >> 10;
  int co   = mb * 16 + (lane & 15);
  int kb   = t * 32 + (lane >> 4) * 8;
  frag_t v;
#pragma unroll
  for (int j = 0; j < 8; ++j) {
    int k = kb + j;
    int tap = k >> 8;
    int ci  = k & 255;
    __hip_bfloat16 h = __float2bfloat16(k4[(co * CINC + ci) * 9 + tap]);
    v[j] = *reinterpret_cast<short*>(&h);
  }
  awr[i] = v;
}

// ---------- main kernel
__global__ __launch_bounds__(256, 3) void conv_occ(
    const __hip_bfloat16* __restrict__ xt,
    const frag_t* __restrict__ awr,
    const float* __restrict__ bias,
    float* __restrict__ out) {
  __shared__ alignas(16) char lds[3 * BUF_SZ];   // 24 KiB -> 3+ blocks/CU

  const int tid  = threadIdx.x;
  const int lane = tid & 63;
  const int wid  = tid >> 6;          // 0..3
  const int wm   = wid >> 1;          // co half of block (0/1): rows wm*64
  const int wn   = wid & 1;           // px half of block (0/1): cols wn*64
  const int fr   = lane & 15;
  const int g    = lane >> 4;         // 0..3 k-chunk

  // grid 1568 = 8 * 196, bijective XCD swizzle; interleave co-tiles so both
  // co halves of a px panel land on the same XCD (B L2 reuse).
  const int bid   = blockIdx.x;
  const int wgid  = (bid & 7) * 196 + (bid >> 3);
  const int ctile = wgid & 1;         // co tile (0/1): co base ctile*128
  const int ptile = wgid >> 1;        // px tile 0..783

  const char* xt_b = (const char*)xt;

  // B staging: 1KB gload = 16 rows x 64B. lane l -> row l>>2, phys chunk l&3.
  // swizzle: LDS[row][phys] holds logical chunk (phys - ((row>>1)&3)) & 3.
  const int lr  = lane >> 2;
  const int sc  = ((((lane & 3) - ((lane >> 3) & 3)) & 3) << 4);

  auto mkB = [&](int jb) -> const char* {
    int px = ptile * 128 + wid * 32 + jb * 16 + lr;
    int b  = px / PIX_PER_IMG;
    int hw = px - b * PIX_PER_IMG;
    int h = hw / WW, w = hw - h * WW;
    return xt_b + (size_t)((b * HP + h) * WP + w) * (CINC * 2) + sc;
  };
  const char* pB0 = mkB(0);
  const char* pB1 = mkB(1);

#define STG(T2, WB) {                                                      \
    int _tap = (T2) >> 3; int _rr = _tap / 3, _ss = _tap - _rr * 3;        \
    size_t _bo = (size_t)(_rr * WP + _ss) * (CINC * 2)                     \
               + (size_t)((T2) & 7) * 64;                                  \
    char* _d = lds + (WB) * BUF_SZ;                                        \
    gload_lds16(pB0 + _bo, _d + wid * 2048 + 0);                           \
    gload_lds16(pB1 + _bo, _d + wid * 2048 + 1024); }

  // A frag loads: frag index (t*16 + mb)*64 + lane; this wave's mb base:
  const frag_t* abase = awr + (size_t)(ctile * 8 + wm * 4) * 64 + lane;

#define ALOAD(T1, FA) {                                                    \
    const frag_t* _p = abase + (size_t)(T1) * (16 * 64);                   \
    _Pragma("unroll") for (int m = 0; m < 4; ++m)                          \
      FA[m] = _p[m * 64]; }

  // B frag reads: row = wn*64 + n*16 + fr -> phys chunk (g + (fr>>1)) & 3
  const int ckr   = (((g + (fr >> 1)) & 3) << 4);
  const int broff = (wn * 64 + fr) * 64 + ckr;

  frag_t fa0[4], fa1[4], fb[4];
  f32x4 acc[4][4] = {};

#define RSL(RB) {                                                          \
    const char* _b = lds + (RB) * BUF_SZ;                                  \
    _Pragma("unroll") for (int n = 0; n < 4; ++n)                          \
      fb[n] = *(const frag_t*)(_b + broff + n * 1024); }

#define MF(FA) {                                                           \
    __builtin_amdgcn_s_setprio(1);                                         \
    _Pragma("unroll") for (int m = 0; m < 4; ++m)                          \
    _Pragma("unroll") for (int n = 0; n < 4; ++n)                          \
      acc[m][n] = __builtin_amdgcn_mfma_f32_16x16x32_bf16(                 \
          FA[m], fb[n], acc[m][n], 0, 0, 0);                               \
    __builtin_amdgcn_s_setprio(0); }

  // body t: stage B(t+2), load A(t+1), read B(t), 16 MFMA.
  // VMEM/body = 2 + 4 = 6 -> vmcnt(6) retires all of body t-1's ops.
#define BODY(T, RB, WB, FCUR, FNXT) {                                      \
    STG((T) + 2, WB);                                                      \
    ALOAD((T) + 1, FNXT);                                                  \
    RSL(RB);                                                               \
    MF(FCUR);                                                              \
    asm volatile("s_waitcnt vmcnt(6)" ::: "memory");                       \
    __builtin_amdgcn_s_barrier();                                          \
    __builtin_amdgcn_sched_barrier(0); }

  // ---- prologue: stage B tiles 0,1; load A tile 0
  STG(0, 0);
  STG(1, 1);
  ALOAD(0, fa0);
  asm volatile("s_waitcnt vmcnt(6)" ::: "memory");   // B(0)'s 2 ops retired
  __builtin_amdgcn_s_barrier();
  __builtin_amdgcn_sched_barrier(0);

  // bodies t = 0..65 (11 x 6; ring mod 3, A-parity mod 2)
  for (int base = 0; base < 66; base += 6) {
    BODY(base + 0, 0, 2, fa0, fa1);
    BODY(base + 1, 1, 0, fa1, fa0);
    BODY(base + 2, 2, 1, fa0, fa1);
    BODY(base + 3, 0, 2, fa1, fa0);
    BODY(base + 4, 1, 0, fa0, fa1);
    BODY(base + 5, 2, 1, fa1, fa0);
  }
  BODY(66, 0, 2, fa0, fa1);
  BODY(67, 1, 0, fa1, fa0);
  BODY(68, 2, 1, fa0, fa1);
  BODY(69, 0, 2, fa1, fa0);   // stages B(71), loads A(70)

  // t = 70: load A(71), read buf1, full drain for the last buffer
  {
    ALOAD(71, fa1);
    RSL(1);
    MF(fa0);
    asm volatile("s_waitcnt vmcnt(0)" ::: "memory");
    __builtin_amdgcn_s_barrier();
    __builtin_amdgcn_sched_barrier(0);
  }
  // t = 71
  {
    RSL(2);
    MF(fa1);
  }

  // ---- epilogue: D layout col=lane&15 (px), row=(lane>>4)*4+reg (co)
  int pb[4], phw[4];
#pragma unroll
  for (int n = 0; n < 4; ++n) {
    int pxg = ptile * 128 + wn * 64 + n * 16 + fr;
    pb[n]  = pxg / PIX_PER_IMG;
    phw[n] = pxg - pb[n] * PIX_PER_IMG;
  }
#pragma unroll
  for (int m = 0; m < 4; ++m) {
#pragma unroll
    for (int rg = 0; rg < 4; ++rg) {
      int co = ctile * 128 + wm * 64 + m * 16 + g * 4 + rg;
      float bv = bias[co];
#pragma unroll
      for (int n = 0; n < 4; ++n)
        out[((size_t)pb[n] * COUTC + co) * PIX_PER_IMG + phw[n]] =
            acc[m][n][rg] + bv;
    }
  }
}

// ---------- correctness fallback if workspace is too small
__global__ void conv_direct(const float* __restrict__ inp,
                            const float* __restrict__ kern,
                            const float* __restrict__ bias,
                            float* __restrict__ out) {
  int idx = blockIdx.x * 256 + threadIdx.x;
  if (idx >= BB * COUTC * PIX_PER_IMG) return;
  int w = idx % WW;
  int t = idx / WW;
  int h = t % HH; t /= HH;
  int co = t % COUTC;
  int b  = t / COUTC;
  float acc = bias[co];
  for (int ci = 0; ci < CINC; ++ci)
    for (int r = 0; r < 3; ++r) {
      int hh = h + r - 1;
      if (hh < 0 || hh >= HH) continue;
      for (int s = 0; s < 3; ++s) {
        int ww2 = w + s - 1;
        if (ww2 < 0 || ww2 >= WW) continue;
        acc += inp[((size_t)(b * CINC + ci) * HH + hh) * WW + ww2] *
               kern[(co * CINC + ci) * 9 + r * 3 + s];
      }
    }
  out[idx] = acc;
}

extern "C" void kernel_launch(void* const* d_in, const int* in_sizes, int n_in,
                              void* d_out, int out_size, void* d_ws, size_t ws_size,
                              hipStream_t stream) {
  const float* inp  = (const float*)d_in[0];
  const float* kern = (const float*)d_in[1];
  const float* bias = (const float*)d_in[2];
  float* out = (float*)d_out;

  size_t need = XT_BYTES + AWR_BYTES;
  if (ws_size < need) {
    int tot = BB * COUTC * PIX_PER_IMG;
    conv_direct<<<(tot + 255) / 256, 256, 0, stream>>>(inp, kern, bias, out);
    return;
  }

  __hip_bfloat16* xt = (__hip_bfloat16*)d_ws;
  frag_t* awr = (frag_t*)((char*)d_ws + XT_BYTES);

  xpose_kernel<<<BB * 4 * HP, 256, 0, stream>>>(inp, xt);
  wprep_pack<<<(AWR_FRAGS + 255) / 256, 256, 0, stream>>>(kern, awr);
  conv_occ<<<2 * (NPIX / 128), 256, 0, stream>>>(xt, awr, bias, out);
}